// Round 11
// baseline (278.509 us; speedup 1.0000x reference)
//
#include <hip/hip_runtime.h>
#include <math.h>

namespace {

constexpr int kB   = 64;
constexpr int kCin = 8;
constexpr int kR   = 800;
constexpr int kNC  = 128;
constexpr int kO   = 16;
constexpr int CT   = 256;   // conversion kernel TPB
constexpr int MT   = 512;   // main kernel TPB
constexpr int NITER = 3;
constexpr size_t WS_W = (size_t)kNC * kO * kR * kCin * sizeof(unsigned short); // 26,214,400
constexpr size_t WS_X = (size_t)kB * kCin * kR * sizeof(unsigned short);       // 819,200

typedef _Float16 half2v __attribute__((ext_vector_type(2)));

__device__ __forceinline__ half2v u2h(unsigned int u) {
  union { unsigned int u; half2v h; } x;
  x.u = u;
  return x.h;
}

__device__ __forceinline__ unsigned short f2h(float f) {
  union { _Float16 h; unsigned short s; } x;
  x.h = (_Float16)f;
  return x.s;
}

// DPP adds: xor1 = quad_perm{1,0,3,2}=0xB1, xor2 = quad_perm{2,3,0,1}=0x4E,
// mir8 = row_half_mirror (0x141): lane i <-> 7-i within each 8-lane half-row.
__device__ __forceinline__ float dpp_xor1_add(float v) {
  const int o = __builtin_amdgcn_mov_dpp(__float_as_int(v), 0xB1, 0xF, 0xF, true);
  return v + __int_as_float(o);
}
__device__ __forceinline__ float dpp_xor2_add(float v) {
  const int o = __builtin_amdgcn_mov_dpp(__float_as_int(v), 0x4E, 0xF, 0xF, true);
  return v + __int_as_float(o);
}
__device__ __forceinline__ float dpp_mir8_add(float v) {
  const int o = __builtin_amdgcn_mov_dpp(__float_as_int(v), 0x141, 0xF, 0xF, true);
  return v + __int_as_float(o);
}

// ---- conversion kernel: two roles by block index --------------------------
//  blk < 3200:  W fp32 [c][r][i][o] -> fp16 [c][r][o][i]  (R11 layout:
//               thread's 16 o-panels for one row are 256 B CONTIGUOUS)
//  blk >= 3200: x fp32 [b][i][r]    -> fp16 [b][r][i]     (R10-proven)
__global__ __launch_bounds__(CT) void conv_w(const float* __restrict__ W,
                                             unsigned short* __restrict__ Wb,
                                             const float* __restrict__ x,
                                             unsigned short* __restrict__ xh) {
  __shared__ float smem[kCin * 804];   // 25.7 KB; W path uses first 16.9 KB
  const int blk = blockIdx.x;
  const int t   = threadIdx.x;

  if (blk < kNC * 25) {
    // ---- W transpose: tile load unchanged; store side re-indexed ----
    float* tile = smem;                // 32 r-rows x 132 (4224 floats)
    const int c  = blk / 25;
    const int rt = blk - c * 25;
    const int r0 = rt * 32;

    const float4* src =
        reinterpret_cast<const float4*>(W + ((size_t)c * kR + r0) * kCin * kO);
    #pragma unroll
    for (int k2 = 0; k2 < 4; ++k2) {
      const int i4  = t + k2 * CT;
      const float4 v = src[i4];
      const int fi = i4 * 4, row = fi >> 7, pos = fi & 127;
      *reinterpret_cast<float4*>(&tile[row * 132 + pos]) = v;
    }
    __syncthreads();

    // o = t&15 so 16 consecutive lanes write one row's 256 B contiguously.
    const int o = t & 15;
    #pragma unroll
    for (int k2 = 0; k2 < 2; ++k2) {
      const int rl = (t >> 4) + 16 * k2;
      unsigned int pk[4];
      #pragma unroll
      for (int q = 0; q < 4; ++q) {
        const unsigned int lo = f2h(tile[rl * 132 + (2 * q + 0) * 16 + o]);
        const unsigned int hi = f2h(tile[rl * 132 + (2 * q + 1) * 16 + o]);
        pk[q] = lo | (hi << 16);
      }
      reinterpret_cast<uint4*>(Wb)[((size_t)c * kR + (r0 + rl)) * kO + o] =
          make_uint4(pk[0], pk[1], pk[2], pk[3]);
    }
  } else {
    // ---- x transpose: one block per b (R10-proven) ----
    const int b = blk - kNC * 25;      // 0..63
    const float4* src =
        reinterpret_cast<const float4*>(x + (size_t)b * kCin * kR);
    #pragma unroll
    for (int k = 0; k < 7; ++k) {
      const int idx = t + k * CT;      // 0..1599 float4
      if (idx < kCin * kR / 4) {
        const float4 v = src[idx];
        const int i = idx / 200;       // 200 float4 per i-plane
        const int r = (idx - i * 200) * 4;
        float* dst = &smem[i * 804 + r];
        dst[0] = v.x; dst[1] = v.y; dst[2] = v.z; dst[3] = v.w;
      }
    }
    __syncthreads();
    #pragma unroll
    for (int k = 0; k < 4; ++k) {
      const int r = t + k * CT;
      if (r < kR) {
        unsigned int pk[4];
        #pragma unroll
        for (int q = 0; q < 4; ++q) {
          const unsigned int lo = f2h(smem[(2 * q + 0) * 804 + r]);
          const unsigned int hi = f2h(smem[(2 * q + 1) * 804 + r]);
          pk[q] = lo | (hi << 16);
        }
        reinterpret_cast<uint4*>(xh)[(size_t)b * kR + r] =
            make_uint4(pk[0], pk[1], pk[2], pk[3]);
      }
    }
  }
}

// ---- main (R11): R10 byte-for-byte EXCEPT W layout [c][r][o][i]: each
// row's 16 W loads come off ONE base address with immediate offsets 0..240 B
// (was 16 computed addresses at 12.8 KB stride — offset:12800 doesn't fit the
// 13-bit signed imm). Removes ~30-60 address-VALU ops from the HEAD of the
// phase-1 dependency chain — the lever class R10 proved productive. fdot2
// sequence unchanged -> bit-identical output. All proven pieces frozen. ----
__global__ __launch_bounds__(MT, 4) void caps_route(
    const float* __restrict__ x, const unsigned short* __restrict__ Wb,
    const unsigned short* __restrict__ xh, float* __restrict__ out) {
  constexpr int RST = 20;               // 17 cols + 3 pad (16B-aligned rows)
  __shared__ float red[128 * RST];      // 10 KB
  __shared__ float shs[RST];

  const int t = threadIdx.x;
  // XCD swizzle: 16 c's per XCD -> fp16 W working set 3.3 MB < 4 MB L2.
  const int j   = blockIdx.x;
  const int xcd = j & 7;
  const int kk  = j >> 3;               // 0..1023
  const int c   = ((kk >> 6) << 3) + xcd;
  const int b   = kk & 63;

  const float* xb  = x + (size_t)b * kCin * kR;
  const bool  has2 = (t < kR - MT);     // t < 288 owns second row r2
  const int   r1   = t, r2 = MT + t;

  // Priors stored packed o-pairs (R0-proven): 8 half2v per row.
  half2v P1[8], P2[8];
  #pragma unroll
  for (int q = 0; q < 8; ++q) P2[q] = half2v{(_Float16)0.f, (_Float16)0.f};

  const uint4* Wc = reinterpret_cast<const uint4*>(Wb) + (size_t)c * kR * kO;
  const uint4* xv = xh ? reinterpret_cast<const uint4*>(xh) + (size_t)b * kR
                       : nullptr;

  // -------- Phase 1: fdot2 rows; explicit 8-deep load chunks ----------------
  {
    const uint4* Wr = Wc + (size_t)r1 * kO;   // one base; imm offsets 0..240
    half2v xp[4];
    if (xv) {
      const uint4 xr = xv[r1];
      xp[0] = u2h(xr.x); xp[1] = u2h(xr.y); xp[2] = u2h(xr.z); xp[3] = u2h(xr.w);
    } else {
      #pragma unroll
      for (int q = 0; q < 4; ++q)
        xp[q] = half2v{(_Float16)xb[(2*q) * kR + r1], (_Float16)xb[(2*q+1) * kR + r1]};
    }
    float p[16];
    #pragma unroll
    for (int ob = 0; ob < 2; ++ob) {
      uint4 w[8];
      #pragma unroll
      for (int u = 0; u < 8; ++u) w[u] = Wr[ob * 8 + u];
      #pragma unroll
      for (int u = 0; u < 8; ++u) {
        float a = __builtin_amdgcn_fdot2(u2h(w[u].x), xp[0], 0.f, false);
        a = __builtin_amdgcn_fdot2(u2h(w[u].y), xp[1], a, false);
        a = __builtin_amdgcn_fdot2(u2h(w[u].z), xp[2], a, false);
        a = __builtin_amdgcn_fdot2(u2h(w[u].w), xp[3], a, false);
        p[ob * 8 + u] = a;
      }
    }
    #pragma unroll
    for (int q = 0; q < 8; ++q)
      P1[q] = half2v{(_Float16)p[2*q], (_Float16)p[2*q+1]};
  }
  if (has2) {
    const uint4* Wr = Wc + (size_t)r2 * kO;
    half2v xp[4];
    if (xv) {
      const uint4 xr = xv[r2];
      xp[0] = u2h(xr.x); xp[1] = u2h(xr.y); xp[2] = u2h(xr.z); xp[3] = u2h(xr.w);
    } else {
      #pragma unroll
      for (int q = 0; q < 4; ++q)
        xp[q] = half2v{(_Float16)xb[(2*q) * kR + r2], (_Float16)xb[(2*q+1) * kR + r2]};
    }
    float p[16];
    #pragma unroll
    for (int ob = 0; ob < 2; ++ob) {
      uint4 w[8];
      #pragma unroll
      for (int u = 0; u < 8; ++u) w[u] = Wr[ob * 8 + u];
      #pragma unroll
      for (int u = 0; u < 8; ++u) {
        float a = __builtin_amdgcn_fdot2(u2h(w[u].x), xp[0], 0.f, false);
        a = __builtin_amdgcn_fdot2(u2h(w[u].y), xp[1], a, false);
        a = __builtin_amdgcn_fdot2(u2h(w[u].z), xp[2], a, false);
        a = __builtin_amdgcn_fdot2(u2h(w[u].w), xp[3], a, false);
        p[ob * 8 + u] = a;
      }
    }
    #pragma unroll
    for (int q = 0; q < 8; ++q)
      P2[q] = half2v{(_Float16)p[2*q], (_Float16)p[2*q+1]};
  }

  // -------- Phase 2: 3 routing iterations (fp32 math, mix-FMA on packed P) --
  float l1 = 0.f, l2 = 0.f;
  #pragma unroll
  for (int it = 0; it < NITER; ++it) {
    const float e1 = (it == 0) ? 1.f : __expf(l1);
    const float e2 = has2 ? ((it == 0) ? 1.f : __expf(l2)) : 0.f;

    float sp[kO + 1];
    sp[kO] = e1 + e2;
    #pragma unroll
    for (int q = 0; q < 8; ++q) {
      sp[2*q]   = e1 * (float)P1[q].x + e2 * (float)P2[q].x;
      sp[2*q+1] = e1 * (float)P1[q].y + e2 * (float)P2[q].y;
    }

    #pragma unroll
    for (int v = 0; v <= kO; ++v) {
      sp[v] = dpp_xor1_add(sp[v]);
      sp[v] = dpp_xor2_add(sp[v]);
    }
    if ((t & 3) == 0) {
      float* row = &red[(t >> 2) * RST];
      #pragma unroll
      for (int q = 0; q < 4; ++q)
        *reinterpret_cast<float4*>(row + 4 * q) =
            make_float4(sp[4*q], sp[4*q+1], sp[4*q+2], sp[4*q+3]);
      row[16] = sp[16];
    }
    __syncthreads();

    // Merged stage 2+3 (R6-proven, zero bank conflicts):
    // t = col*8+q; 8-lane DPP group (fixed col) sums the 8 q-partials.
    if (t < 136) {
      const int q = t & 7, col = t >> 3;
      float a = 0.f;
      #pragma unroll
      for (int rr = 0; rr < 16; ++rr) a += red[(rr * 8 + q) * RST + col];
      a = dpp_xor1_add(a);
      a = dpp_xor2_add(a);
      a = dpp_mir8_add(a);
      if (q == 0) shs[col] = a;
    }
    __syncthreads();

    const float Zi = 1.f / shs[kO];
    float ss = 0.f;
    #pragma unroll
    for (int o = 0; o < kO; ++o) ss += shs[o] * shs[o];
    const float sn = ss * Zi * Zi;
    const float g  = Zi * sqrtf(sn) / (1.f + sn);

    if (it < NITER - 1) {
      float d1 = 0.f, d2 = 0.f;
      #pragma unroll
      for (int q = 0; q < 8; ++q) {
        d1 += (float)P1[q].x * shs[2*q] + (float)P1[q].y * shs[2*q+1];
        d2 += (float)P2[q].x * shs[2*q] + (float)P2[q].y * shs[2*q+1];
      }
      l1 += d1 * g;
      if (has2) l2 += d2 * g;
    } else {
      if (t < kO) out[(size_t)b * kO * kNC + t * kNC + c] = shs[t] * g;
    }
  }
}

// ---- fallback (no workspace): fp32 W direct — R6-proven kernel ------------
__global__ __launch_bounds__(MT, 4) void caps_route_f32(
    const float* __restrict__ x, const float* __restrict__ W,
    float* __restrict__ out) {
  constexpr int RST = 20;
  __shared__ float red[128 * RST];
  __shared__ float shs[RST];

  const int t   = threadIdx.x;
  const int j   = blockIdx.x;
  const int xcd = j & 7;
  const int kk  = j >> 3;
  const int c   = ((kk >> 6) << 3) + xcd;
  const int b   = kk & 63;

  const float* xb  = x + (size_t)b * kCin * kR;
  const bool  has2 = (t < kR - MT);
  const int   r1   = t, r2 = MT + t;

  float P1[kO], P2[kO];
  #pragma unroll
  for (int o = 0; o < kO; ++o) P2[o] = 0.f;
  {
    float xa[kCin];
    #pragma unroll
    for (int i = 0; i < kCin; ++i) xa[i] = xb[i * kR + r1];
    const float* Wc = W + ((size_t)c * kR + r1) * kCin * kO;
    #pragma unroll
    for (int o = 0; o < kO; ++o) {
      float acc = 0.f;
      #pragma unroll
      for (int i = 0; i < kCin; ++i) acc += xa[i] * Wc[i * kO + o];
      P1[o] = acc;
    }
  }
  if (has2) {
    float xa[kCin];
    #pragma unroll
    for (int i = 0; i < kCin; ++i) xa[i] = xb[i * kR + r2];
    const float* Wc = W + ((size_t)c * kR + r2) * kCin * kO;
    #pragma unroll
    for (int o = 0; o < kO; ++o) {
      float acc = 0.f;
      #pragma unroll
      for (int i = 0; i < kCin; ++i) acc += xa[i] * Wc[i * kO + o];
      P2[o] = acc;
    }
  }

  float l1 = 0.f, l2 = 0.f;
  #pragma unroll
  for (int it = 0; it < NITER; ++it) {
    const float e1 = (it == 0) ? 1.f : __expf(l1);
    const float e2 = has2 ? ((it == 0) ? 1.f : __expf(l2)) : 0.f;
    float sp[kO + 1];
    sp[kO] = e1 + e2;
    #pragma unroll
    for (int o = 0; o < kO; ++o) sp[o] = e1 * P1[o] + e2 * P2[o];
    #pragma unroll
    for (int v = 0; v <= kO; ++v) {
      sp[v] = dpp_xor1_add(sp[v]);
      sp[v] = dpp_xor2_add(sp[v]);
    }
    if ((t & 3) == 0) {
      float* row = &red[(t >> 2) * RST];
      #pragma unroll
      for (int q = 0; q < 4; ++q)
        *reinterpret_cast<float4*>(row + 4 * q) =
            make_float4(sp[4*q], sp[4*q+1], sp[4*q+2], sp[4*q+3]);
      row[16] = sp[16];
    }
    __syncthreads();
    if (t < 136) {
      const int q = t & 7, col = t >> 3;
      float a = 0.f;
      #pragma unroll
      for (int rr = 0; rr < 16; ++rr) a += red[(rr * 8 + q) * RST + col];
      a = dpp_xor1_add(a);
      a = dpp_xor2_add(a);
      a = dpp_mir8_add(a);
      if (q == 0) shs[col] = a;
    }
    __syncthreads();
    const float Zi = 1.f / shs[kO];
    float ss = 0.f;
    #pragma unroll
    for (int o = 0; o < kO; ++o) ss += shs[o] * shs[o];
    const float sn = ss * Zi * Zi;
    const float g  = Zi * sqrtf(sn) / (1.f + sn);
    if (it < NITER - 1) {
      float d1 = 0.f, d2 = 0.f;
      #pragma unroll
      for (int o = 0; o < kO; ++o) { d1 += P1[o] * shs[o]; d2 += P2[o] * shs[o]; }
      l1 += d1 * g;
      if (has2) l2 += d2 * g;
    } else {
      if (t < kO) out[(size_t)b * kO * kNC + t * kNC + c] = shs[t] * g;
    }
  }
}

}  // namespace

extern "C" void kernel_launch(void* const* d_in, const int* in_sizes, int n_in,
                              void* d_out, int out_size, void* d_ws, size_t ws_size,
                              hipStream_t stream) {
  const float* x = (const float*)d_in[0];   // [64, 8, 800] fp32
  const float* W = (const float*)d_in[1];   // [128, 800, 8, 16] fp32
  float* out = (float*)d_out;               // [64, 16, 128] fp32
  (void)in_sizes; (void)n_in; (void)out_size;

  if (ws_size >= WS_W + WS_X) {
    unsigned short* Wb = (unsigned short*)d_ws;
    unsigned short* xh = (unsigned short*)((char*)d_ws + WS_W);
    conv_w<<<dim3(kNC * 25 + kB), dim3(CT), 0, stream>>>(W, Wb, x, xh);
    caps_route<<<dim3(kNC * kB), dim3(MT), 0, stream>>>(x, Wb, xh, out);
  } else if (ws_size >= WS_W) {
    unsigned short* Wb = (unsigned short*)d_ws;
    conv_w<<<dim3(kNC * 25), dim3(CT), 0, stream>>>(W, Wb, x, nullptr);
    caps_route<<<dim3(kNC * kB), dim3(MT), 0, stream>>>(x, Wb, nullptr, out);
  } else {
    caps_route_f32<<<dim3(kNC * kB), dim3(MT), 0, stream>>>(x, W, out);
  }
}

// Round 12
// 195.146 us; speedup vs baseline: 1.4272x; 1.4272x over previous
//
#include <hip/hip_runtime.h>
#include <math.h>

namespace {

constexpr int kB   = 64;
constexpr int kCin = 8;
constexpr int kR   = 800;
constexpr int kNC  = 128;
constexpr int kO   = 16;
constexpr int CT   = 256;   // conversion kernel TPB
constexpr int MT   = 512;   // main kernel TPB
constexpr int NITER = 3;
constexpr size_t WS_W = (size_t)kNC * kO * kR * kCin * sizeof(unsigned short); // 26,214,400
constexpr size_t WS_X = (size_t)kB * kCin * kR * sizeof(unsigned short);       // 819,200

typedef _Float16 half2v __attribute__((ext_vector_type(2)));

__device__ __forceinline__ half2v u2h(unsigned int u) {
  union { unsigned int u; half2v h; } x;
  x.u = u;
  return x.h;
}

__device__ __forceinline__ unsigned short f2h(float f) {
  union { _Float16 h; unsigned short s; } x;
  x.h = (_Float16)f;
  return x.s;
}

// DPP adds: xor1 = quad_perm{1,0,3,2}=0xB1, xor2 = quad_perm{2,3,0,1}=0x4E,
// mir8 = row_half_mirror (0x141): lane i <-> 7-i within each 8-lane half-row.
__device__ __forceinline__ float dpp_xor1_add(float v) {
  const int o = __builtin_amdgcn_mov_dpp(__float_as_int(v), 0xB1, 0xF, 0xF, true);
  return v + __int_as_float(o);
}
__device__ __forceinline__ float dpp_xor2_add(float v) {
  const int o = __builtin_amdgcn_mov_dpp(__float_as_int(v), 0x4E, 0xF, 0xF, true);
  return v + __int_as_float(o);
}
__device__ __forceinline__ float dpp_mir8_add(float v) {
  const int o = __builtin_amdgcn_mov_dpp(__float_as_int(v), 0x141, 0xF, 0xF, true);
  return v + __int_as_float(o);
}

// ---- conversion kernel: two roles by block index --------------------------
//  blk < 3200:  W fp32 [c][r][i][o] -> fp16 [c][o][r][i]  (R1-proven; wave-
//               coalesced consumer loads: lane t reads (o*800+t)*16B, 16B
//               lane stride. R11's [c][r][o][i] broke this -> 64 lines/load)
//  blk >= 3200: x fp32 [b][i][r]    -> fp16 [b][r][i]     (R10-proven)
__global__ __launch_bounds__(CT) void conv_w(const float* __restrict__ W,
                                             unsigned short* __restrict__ Wb,
                                             const float* __restrict__ x,
                                             unsigned short* __restrict__ xh) {
  __shared__ float smem[kCin * 804];   // 25.7 KB; W path uses first 16.9 KB
  const int blk = blockIdx.x;
  const int t   = threadIdx.x;

  if (blk < kNC * 25) {
    // ---- W transpose (R1-proven path) ----
    float* tile = smem;                // 32 r-rows x 132 (4224 floats)
    const int c  = blk / 25;
    const int rt = blk - c * 25;
    const int r0 = rt * 32;

    const float4* src =
        reinterpret_cast<const float4*>(W + ((size_t)c * kR + r0) * kCin * kO);
    #pragma unroll
    for (int k2 = 0; k2 < 4; ++k2) {
      const int i4  = t + k2 * CT;
      const float4 v = src[i4];
      const int fi = i4 * 4, row = fi >> 7, pos = fi & 127;
      *reinterpret_cast<float4*>(&tile[row * 132 + pos]) = v;
    }
    __syncthreads();

    const int o = t >> 4;
    #pragma unroll
    for (int k2 = 0; k2 < 2; ++k2) {
      const int rl = (t & 15) + 16 * k2;
      unsigned int pk[4];
      #pragma unroll
      for (int q = 0; q < 4; ++q) {
        const unsigned int lo = f2h(tile[rl * 132 + (2 * q + 0) * 16 + o]);
        const unsigned int hi = f2h(tile[rl * 132 + (2 * q + 1) * 16 + o]);
        pk[q] = lo | (hi << 16);
      }
      reinterpret_cast<uint4*>(Wb)[(size_t)(c * kO + o) * kR + (r0 + rl)] =
          make_uint4(pk[0], pk[1], pk[2], pk[3]);
    }
  } else {
    // ---- x transpose: one block per b (R10-proven) ----
    const int b = blk - kNC * 25;      // 0..63
    const float4* src =
        reinterpret_cast<const float4*>(x + (size_t)b * kCin * kR);
    #pragma unroll
    for (int k = 0; k < 7; ++k) {
      const int idx = t + k * CT;      // 0..1599 float4
      if (idx < kCin * kR / 4) {
        const float4 v = src[idx];
        const int i = idx / 200;       // 200 float4 per i-plane
        const int r = (idx - i * 200) * 4;
        float* dst = &smem[i * 804 + r];
        dst[0] = v.x; dst[1] = v.y; dst[2] = v.z; dst[3] = v.w;
      }
    }
    __syncthreads();
    #pragma unroll
    for (int k = 0; k < 4; ++k) {
      const int r = t + k * CT;
      if (r < kR) {
        unsigned int pk[4];
        #pragma unroll
        for (int q = 0; q < 4; ++q) {
          const unsigned int lo = f2h(smem[(2 * q + 0) * 804 + r]);
          const unsigned int hi = f2h(smem[(2 * q + 1) * 804 + r]);
          pk[q] = lo | (hi << 16);
        }
        reinterpret_cast<uint4*>(xh)[(size_t)b * kR + r] =
            make_uint4(pk[0], pk[1], pk[2], pk[3]);
      }
    }
  }
}

// ---- main: R10 exactly — the session's verified best (118.3 us).
// R11's [c][r][o][i] W layout regressed 118->202 us: per-thread-contiguous
// panels put consecutive LANES 256 B apart (64 cache lines per wave load vs
// 16). KEEP [c][o][r][i]: 16 computed addresses per row but every wave load
// is 1 KB coalesced. Frozen pieces: single-b, 8192 blocks, (512,4), VGPR
// 64-cap sweet spot (reg law: cap=256/arg2), 8-deep W chunks, packed-uint4 x
// path (R10, -11us), merged zero-conflict DPP reduce (R6), mix-FMA phase 2
// (R9). ----
__global__ __launch_bounds__(MT, 4) void caps_route(
    const float* __restrict__ x, const unsigned short* __restrict__ Wb,
    const unsigned short* __restrict__ xh, float* __restrict__ out) {
  constexpr int RST = 20;               // 17 cols + 3 pad (16B-aligned rows)
  __shared__ float red[128 * RST];      // 10 KB
  __shared__ float shs[RST];

  const int t = threadIdx.x;
  // XCD swizzle: 16 c's per XCD -> fp16 W working set 3.3 MB < 4 MB L2.
  const int j   = blockIdx.x;
  const int xcd = j & 7;
  const int kk  = j >> 3;               // 0..1023
  const int c   = ((kk >> 6) << 3) + xcd;
  const int b   = kk & 63;

  const float* xb  = x + (size_t)b * kCin * kR;
  const bool  has2 = (t < kR - MT);     // t < 288 owns second row r2
  const int   r1   = t, r2 = MT + t;

  // Priors stored packed o-pairs (R0-proven): 8 half2v per row.
  half2v P1[8], P2[8];
  #pragma unroll
  for (int q = 0; q < 8; ++q) P2[q] = half2v{(_Float16)0.f, (_Float16)0.f};

  const uint4* Wc = reinterpret_cast<const uint4*>(Wb) + (size_t)c * kO * kR;
  const uint4* xv = xh ? reinterpret_cast<const uint4*>(xh) + (size_t)b * kR
                       : nullptr;

  // -------- Phase 1: fdot2 rows; explicit 8-deep load chunks ----------------
  {
    half2v xp[4];
    if (xv) {
      const uint4 xr = xv[r1];
      xp[0] = u2h(xr.x); xp[1] = u2h(xr.y); xp[2] = u2h(xr.z); xp[3] = u2h(xr.w);
    } else {
      #pragma unroll
      for (int q = 0; q < 4; ++q)
        xp[q] = half2v{(_Float16)xb[(2*q) * kR + r1], (_Float16)xb[(2*q+1) * kR + r1]};
    }
    float p[16];
    #pragma unroll
    for (int ob = 0; ob < 2; ++ob) {
      uint4 w[8];
      #pragma unroll
      for (int u = 0; u < 8; ++u) w[u] = Wc[(size_t)(ob * 8 + u) * kR + r1];
      #pragma unroll
      for (int u = 0; u < 8; ++u) {
        float a = __builtin_amdgcn_fdot2(u2h(w[u].x), xp[0], 0.f, false);
        a = __builtin_amdgcn_fdot2(u2h(w[u].y), xp[1], a, false);
        a = __builtin_amdgcn_fdot2(u2h(w[u].z), xp[2], a, false);
        a = __builtin_amdgcn_fdot2(u2h(w[u].w), xp[3], a, false);
        p[ob * 8 + u] = a;
      }
    }
    #pragma unroll
    for (int q = 0; q < 8; ++q)
      P1[q] = half2v{(_Float16)p[2*q], (_Float16)p[2*q+1]};
  }
  if (has2) {
    half2v xp[4];
    if (xv) {
      const uint4 xr = xv[r2];
      xp[0] = u2h(xr.x); xp[1] = u2h(xr.y); xp[2] = u2h(xr.z); xp[3] = u2h(xr.w);
    } else {
      #pragma unroll
      for (int q = 0; q < 4; ++q)
        xp[q] = half2v{(_Float16)xb[(2*q) * kR + r2], (_Float16)xb[(2*q+1) * kR + r2]};
    }
    float p[16];
    #pragma unroll
    for (int ob = 0; ob < 2; ++ob) {
      uint4 w[8];
      #pragma unroll
      for (int u = 0; u < 8; ++u) w[u] = Wc[(size_t)(ob * 8 + u) * kR + r2];
      #pragma unroll
      for (int u = 0; u < 8; ++u) {
        float a = __builtin_amdgcn_fdot2(u2h(w[u].x), xp[0], 0.f, false);
        a = __builtin_amdgcn_fdot2(u2h(w[u].y), xp[1], a, false);
        a = __builtin_amdgcn_fdot2(u2h(w[u].z), xp[2], a, false);
        a = __builtin_amdgcn_fdot2(u2h(w[u].w), xp[3], a, false);
        p[ob * 8 + u] = a;
      }
    }
    #pragma unroll
    for (int q = 0; q < 8; ++q)
      P2[q] = half2v{(_Float16)p[2*q], (_Float16)p[2*q+1]};
  }

  // -------- Phase 2: 3 routing iterations (fp32 math, mix-FMA on packed P) --
  float l1 = 0.f, l2 = 0.f;
  #pragma unroll
  for (int it = 0; it < NITER; ++it) {
    const float e1 = (it == 0) ? 1.f : __expf(l1);
    const float e2 = has2 ? ((it == 0) ? 1.f : __expf(l2)) : 0.f;

    float sp[kO + 1];
    sp[kO] = e1 + e2;
    #pragma unroll
    for (int q = 0; q < 8; ++q) {
      sp[2*q]   = e1 * (float)P1[q].x + e2 * (float)P2[q].x;
      sp[2*q+1] = e1 * (float)P1[q].y + e2 * (float)P2[q].y;
    }

    #pragma unroll
    for (int v = 0; v <= kO; ++v) {
      sp[v] = dpp_xor1_add(sp[v]);
      sp[v] = dpp_xor2_add(sp[v]);
    }
    if ((t & 3) == 0) {
      float* row = &red[(t >> 2) * RST];
      #pragma unroll
      for (int q = 0; q < 4; ++q)
        *reinterpret_cast<float4*>(row + 4 * q) =
            make_float4(sp[4*q], sp[4*q+1], sp[4*q+2], sp[4*q+3]);
      row[16] = sp[16];
    }
    __syncthreads();

    // Merged stage 2+3 (R6-proven, zero bank conflicts):
    // t = col*8+q; 8-lane DPP group (fixed col) sums the 8 q-partials.
    if (t < 136) {
      const int q = t & 7, col = t >> 3;
      float a = 0.f;
      #pragma unroll
      for (int rr = 0; rr < 16; ++rr) a += red[(rr * 8 + q) * RST + col];
      a = dpp_xor1_add(a);
      a = dpp_xor2_add(a);
      a = dpp_mir8_add(a);
      if (q == 0) shs[col] = a;
    }
    __syncthreads();

    const float Zi = 1.f / shs[kO];
    float ss = 0.f;
    #pragma unroll
    for (int o = 0; o < kO; ++o) ss += shs[o] * shs[o];
    const float sn = ss * Zi * Zi;
    const float g  = Zi * sqrtf(sn) / (1.f + sn);

    if (it < NITER - 1) {
      float d1 = 0.f, d2 = 0.f;
      #pragma unroll
      for (int q = 0; q < 8; ++q) {
        d1 += (float)P1[q].x * shs[2*q] + (float)P1[q].y * shs[2*q+1];
        d2 += (float)P2[q].x * shs[2*q] + (float)P2[q].y * shs[2*q+1];
      }
      l1 += d1 * g;
      if (has2) l2 += d2 * g;
    } else {
      if (t < kO) out[(size_t)b * kO * kNC + t * kNC + c] = shs[t] * g;
    }
  }
}

// ---- fallback (no workspace): fp32 W direct — R6-proven kernel ------------
__global__ __launch_bounds__(MT, 4) void caps_route_f32(
    const float* __restrict__ x, const float* __restrict__ W,
    float* __restrict__ out) {
  constexpr int RST = 20;
  __shared__ float red[128 * RST];
  __shared__ float shs[RST];

  const int t   = threadIdx.x;
  const int j   = blockIdx.x;
  const int xcd = j & 7;
  const int kk  = j >> 3;
  const int c   = ((kk >> 6) << 3) + xcd;
  const int b   = kk & 63;

  const float* xb  = x + (size_t)b * kCin * kR;
  const bool  has2 = (t < kR - MT);
  const int   r1   = t, r2 = MT + t;

  float P1[kO], P2[kO];
  #pragma unroll
  for (int o = 0; o < kO; ++o) P2[o] = 0.f;
  {
    float xa[kCin];
    #pragma unroll
    for (int i = 0; i < kCin; ++i) xa[i] = xb[i * kR + r1];
    const float* Wc = W + ((size_t)c * kR + r1) * kCin * kO;
    #pragma unroll
    for (int o = 0; o < kO; ++o) {
      float acc = 0.f;
      #pragma unroll
      for (int i = 0; i < kCin; ++i) acc += xa[i] * Wc[i * kO + o];
      P1[o] = acc;
    }
  }
  if (has2) {
    float xa[kCin];
    #pragma unroll
    for (int i = 0; i < kCin; ++i) xa[i] = xb[i * kR + r2];
    const float* Wc = W + ((size_t)c * kR + r2) * kCin * kO;
    #pragma unroll
    for (int o = 0; o < kO; ++o) {
      float acc = 0.f;
      #pragma unroll
      for (int i = 0; i < kCin; ++i) acc += xa[i] * Wc[i * kO + o];
      P2[o] = acc;
    }
  }

  float l1 = 0.f, l2 = 0.f;
  #pragma unroll
  for (int it = 0; it < NITER; ++it) {
    const float e1 = (it == 0) ? 1.f : __expf(l1);
    const float e2 = has2 ? ((it == 0) ? 1.f : __expf(l2)) : 0.f;
    float sp[kO + 1];
    sp[kO] = e1 + e2;
    #pragma unroll
    for (int o = 0; o < kO; ++o) sp[o] = e1 * P1[o] + e2 * P2[o];
    #pragma unroll
    for (int v = 0; v <= kO; ++v) {
      sp[v] = dpp_xor1_add(sp[v]);
      sp[v] = dpp_xor2_add(sp[v]);
    }
    if ((t & 3) == 0) {
      float* row = &red[(t >> 2) * RST];
      #pragma unroll
      for (int q = 0; q < 4; ++q)
        *reinterpret_cast<float4*>(row + 4 * q) =
            make_float4(sp[4*q], sp[4*q+1], sp[4*q+2], sp[4*q+3]);
      row[16] = sp[16];
    }
    __syncthreads();
    if (t < 136) {
      const int q = t & 7, col = t >> 3;
      float a = 0.f;
      #pragma unroll
      for (int rr = 0; rr < 16; ++rr) a += red[(rr * 8 + q) * RST + col];
      a = dpp_xor1_add(a);
      a = dpp_xor2_add(a);
      a = dpp_mir8_add(a);
      if (q == 0) shs[col] = a;
    }
    __syncthreads();
    const float Zi = 1.f / shs[kO];
    float ss = 0.f;
    #pragma unroll
    for (int o = 0; o < kO; ++o) ss += shs[o] * shs[o];
    const float sn = ss * Zi * Zi;
    const float g  = Zi * sqrtf(sn) / (1.f + sn);
    if (it < NITER - 1) {
      float d1 = 0.f, d2 = 0.f;
      #pragma unroll
      for (int o = 0; o < kO; ++o) { d1 += P1[o] * shs[o]; d2 += P2[o] * shs[o]; }
      l1 += d1 * g;
      if (has2) l2 += d2 * g;
    } else {
      if (t < kO) out[(size_t)b * kO * kNC + t * kNC + c] = shs[t] * g;
    }
  }
}

}  // namespace

extern "C" void kernel_launch(void* const* d_in, const int* in_sizes, int n_in,
                              void* d_out, int out_size, void* d_ws, size_t ws_size,
                              hipStream_t stream) {
  const float* x = (const float*)d_in[0];   // [64, 8, 800] fp32
  const float* W = (const float*)d_in[1];   // [128, 800, 8, 16] fp32
  float* out = (float*)d_out;               // [64, 16, 128] fp32
  (void)in_sizes; (void)n_in; (void)out_size;

  if (ws_size >= WS_W + WS_X) {
    unsigned short* Wb = (unsigned short*)d_ws;
    unsigned short* xh = (unsigned short*)((char*)d_ws + WS_W);
    conv_w<<<dim3(kNC * 25 + kB), dim3(CT), 0, stream>>>(W, Wb, x, xh);
    caps_route<<<dim3(kNC * kB), dim3(MT), 0, stream>>>(x, Wb, xh, out);
  } else if (ws_size >= WS_W) {
    unsigned short* Wb = (unsigned short*)d_ws;
    conv_w<<<dim3(kNC * 25), dim3(CT), 0, stream>>>(W, Wb, x, nullptr);
    caps_route<<<dim3(kNC * kB), dim3(MT), 0, stream>>>(x, Wb, nullptr, out);
  } else {
    caps_route_f32<<<dim3(kNC * kB), dim3(MT), 0, stream>>>(x, W, out);
  }
}